// Round 4
// baseline (431.646 us; speedup 1.0000x reference)
//
#include <hip/hip_runtime.h>
#include <hip/hip_bf16.h>

#define N_NODES 100000
#define E_EDGES 640000
// channels: IN 256, HID 128, OUT 64+64

typedef __attribute__((ext_vector_type(8))) short short8;
typedef __attribute__((ext_vector_type(4))) float float4v;

__device__ __forceinline__ float bf2f(unsigned int u16) {
    union { unsigned int i; float f; } c; c.i = u16 << 16; return c.f;
}
__device__ __forceinline__ unsigned short f2bf(float f) {
    union { float f; unsigned int i; } c; c.f = f;
    unsigned int x = c.i;
    unsigned int r = (x + 0x7fffu + ((x >> 16) & 1u)) >> 16;   // RNE
    return (unsigned short)r;
}

// async 16B global->LDS (m97 pattern); LDS dst = wave-uniform base + lane*16
#define ASYNC16(g, l)                                                          \
    __builtin_amdgcn_global_load_lds(                                          \
        (const __attribute__((address_space(1))) void*)(g),                    \
        (__attribute__((address_space(3))) void*)(l), 16, 0, 0)

// ---------------- workspace layout (bytes) ----------------
#define WS_HIST    0          // int[100000]
#define WS_CURSOR  524288     // int[100000]   (memset together with hist)
#define WS_OFFS    1048576    // int[100000]
#define WS_DINV    1572864    // float[100000]
#define WS_BSUMS   2097152    // int[256]
#define WS_EIDX    2621440    // int2[640000]  {src, bits(weight)}
#define WS_WP1     7864320    // bf16[128][256] packed W1^T
#define WS_WP2     7929856    // bf16[128][128] packed [Wmu|Wlv]^T
#define WS_H0      7962624    // bf16[100000*128]  x@W1
#define WS_H       33562624   // bf16[100000*128]  relu(A_hat h0 + b1)
// total ~59.2 MB

// ---------------- setup kernels ----------------
__global__ __launch_bounds__(256) void k_hist(const int* __restrict__ dst, int* __restrict__ hist) {
    int e = blockIdx.x * 256 + threadIdx.x;
    if (e < E_EDGES) atomicAdd(&hist[dst[e]], 1);
}

// scan level 1 (+ dinv computed on the side)
__global__ __launch_bounds__(256) void k_scan1(const int* __restrict__ hist,
                                               int* __restrict__ offs,
                                               int* __restrict__ bsums,
                                               float* __restrict__ dinv) {
    __shared__ int sd[256];
    int t = threadIdx.x;
    int base = blockIdx.x * 1024 + t * 4;
    int v[4];
#pragma unroll
    for (int j = 0; j < 4; ++j) v[j] = (base + j < N_NODES) ? hist[base + j] : 0;
#pragma unroll
    for (int j = 0; j < 4; ++j)
        if (base + j < N_NODES) dinv[base + j] = rsqrtf((float)(v[j] + 1));
    int s = v[0] + v[1] + v[2] + v[3];
    sd[t] = s;
    __syncthreads();
    for (int d = 1; d < 256; d <<= 1) {
        int x = (t >= d) ? sd[t - d] : 0;
        __syncthreads();
        sd[t] += x;
        __syncthreads();
    }
    int excl = sd[t] - s;
    if (t == 255) bsums[blockIdx.x] = sd[255];
    int run = excl;
#pragma unroll
    for (int j = 0; j < 4; ++j) {
        if (base + j < N_NODES) offs[base + j] = run;
        run += v[j];
    }
}

__global__ __launch_bounds__(128) void k_scan2(int* __restrict__ bsums, int nb) {
    __shared__ int sd[128];
    int t = threadIdx.x;
    int v = (t < nb) ? bsums[t] : 0;
    sd[t] = v;
    __syncthreads();
    for (int d = 1; d < 128; d <<= 1) {
        int x = (t >= d) ? sd[t - d] : 0;
        __syncthreads();
        sd[t] += x;
        __syncthreads();
    }
    if (t < nb) bsums[t] = sd[t] - v;
}

__global__ __launch_bounds__(256) void k_scan3(int* __restrict__ offs, const int* __restrict__ bsums) {
    int i = blockIdx.x * 256 + threadIdx.x;
    if (i < N_NODES) offs[i] += bsums[i >> 10];
}

// CSR fill: (src, weight) packed into one int2 -> one scattered line per edge
__global__ __launch_bounds__(256) void k_fill(const int* __restrict__ src, const int* __restrict__ dst,
                                              const int* __restrict__ offs, int* __restrict__ cursor,
                                              const float* __restrict__ dinv,
                                              int2* __restrict__ eidx) {
    int e = blockIdx.x * 256 + threadIdx.x;
    if (e < E_EDGES) {
        int s = src[e], d = dst[e];
        int p = offs[d] + atomicAdd(&cursor[d], 1);
        int2 v;
        v.x = s;
        v.y = __float_as_int(dinv[s] * dinv[d]);
        eidx[p] = v;
    }
}

// pack weights to bf16 [n][k] (B^T) layout; W2 = [Wmu | Wlv] columns
__global__ __launch_bounds__(256) void k_pack(const float* __restrict__ W1,
                                              const float* __restrict__ Wmu,
                                              const float* __restrict__ Wlv,
                                              unsigned short* __restrict__ Wp1,
                                              unsigned short* __restrict__ Wp2) {
    int i = blockIdx.x * 256 + threadIdx.x;
    if (i < 256 * 128) {
        int k = i >> 7, n = i & 127;
        Wp1[n * 256 + k] = f2bf(W1[i]);
    }
    if (i < 128 * 128) {
        int k = i >> 7, n = i & 127;
        float w = (n < 64) ? Wmu[k * 64 + n] : Wlv[k * 64 + (n - 64)];
        Wp2[n * 128 + k] = f2bf(w);
    }
}

// ---------------- GEMM1: h0[N][128] = bf16(x[N][256]) @ W1 ----------------
// A fp32 staged via global_load_lds w/ XOR-swizzled source mapping:
//   LDS chunk position j of row r holds kq = j ^ (r&7)  (16B fp32 chunks, 8/row)
// -> fragment ds_read_b128 banks: (j0*4..+3), j0=(q*2)^(r&7): 2-way max (free).
__global__ __launch_bounds__(256) void k_mgemm1(const float* __restrict__ A,
                                                const unsigned short* __restrict__ Bpack,
                                                unsigned short* __restrict__ out) {
    __shared__ float As[128 * 32];          // 16 KB, one K-chunk, swizzled
    __shared__ unsigned short Bs[128 * 40]; // 10 KB, padded stride 40
    int tid = threadIdx.x;
    int row0 = blockIdx.x * 128;
    int wave = tid >> 6, lane = tid & 63;
    int c = lane & 15, q = lane >> 4;
    int wrow = (wave >> 1) * 64, wcol = (wave & 1) * 64;

    float4v acc[4][4];
#pragma unroll
    for (int i = 0; i < 4; ++i)
#pragma unroll
        for (int j = 0; j < 4; ++j) acc[i][j] = (float4v){0.f, 0.f, 0.f, 0.f};

    int srow = tid >> 1;          // B stage: n-row
    int shalf = (tid & 1) * 16;   // B stage: k half

    for (int k0 = 0; k0 < 256; k0 += 32) {
        // B tile (VGPR roundtrip, small + L2-hot)
        const unsigned short* bsrc = Bpack + (size_t)srow * 256 + k0 + shalf;
        short8 b0 = *(const short8*)(bsrc);
        short8 b1 = *(const short8*)(bsrc + 8);
        // A tile: async 16B/lane, 4 rounds x 4 waves cover 128 rows
#pragma unroll
        for (int t = 0; t < 4; ++t) {
            int S = (t * 4 + wave) * 64 + lane;   // slot
            int row = S >> 3, j = S & 7;
            int kq = j ^ (row & 7);
            const float* g = A + (size_t)(row0 + row) * 256 + k0 + kq * 4;
            float* ldst = As + (t * 4 + wave) * 256;   // wave-uniform base
            if (row0 + row < N_NODES) ASYNC16(g, ldst);
        }
        *(short8*)(&Bs[srow * 40 + shalf])     = b0;
        *(short8*)(&Bs[srow * 40 + shalf + 8]) = b1;
        __syncthreads();

        short8 af[4], bfr[4];
#pragma unroll
        for (int mt = 0; mt < 4; ++mt) {
            int r = wrow + mt * 16 + c;
            int j0 = (q * 2) ^ (r & 7);
            float4v fa = *(const float4v*)(&As[r * 32 + j0 * 4]);        // k = q*8..+3
            float4v fb = *(const float4v*)(&As[r * 32 + (j0 ^ 1) * 4]);  // k = q*8+4..+7
            short8 s;
#pragma unroll
            for (int jj = 0; jj < 4; ++jj) s[jj]     = (short)f2bf(fa[jj]);
#pragma unroll
            for (int jj = 0; jj < 4; ++jj) s[4 + jj] = (short)f2bf(fb[jj]);
            af[mt] = s;
        }
#pragma unroll
        for (int nt = 0; nt < 4; ++nt)
            bfr[nt] = *(const short8*)(&Bs[(wcol + nt * 16 + c) * 40 + q * 8]);
#pragma unroll
        for (int mt = 0; mt < 4; ++mt)
#pragma unroll
            for (int nt = 0; nt < 4; ++nt)
                acc[mt][nt] = __builtin_amdgcn_mfma_f32_16x16x32_bf16(af[mt], bfr[nt], acc[mt][nt], 0, 0, 0);
        __syncthreads();
    }

    // epilogue: bf16 out. D: col = lane&15, row = q*4 + reg
#pragma unroll
    for (int mt = 0; mt < 4; ++mt) {
#pragma unroll
        for (int i = 0; i < 4; ++i) {
            int row = row0 + wrow + mt * 16 + q * 4 + i;
            if (row >= N_NODES) continue;
#pragma unroll
            for (int nt = 0; nt < 4; ++nt) {
                int cc = wcol + nt * 16 + c;
                out[(size_t)row * 128 + cc] = f2bf(acc[mt][nt][i]);
            }
        }
    }
}

// ---------------- agg1: h = relu(A_hat h0 + b1), bf16 in/out ----------------
// one wave per node; lane l = channels {2l,2l+1}; edges prefetched lane-parallel
__global__ __launch_bounds__(256) void k_agg1(const unsigned int* __restrict__ in,
                                              unsigned int* __restrict__ out,
                                              const float* __restrict__ dinv,
                                              const int2* __restrict__ eidx,
                                              const int* __restrict__ offs,
                                              const int* __restrict__ cnt,
                                              const float* __restrict__ bias) {
    int wid = (blockIdx.x * 256 + threadIdx.x) >> 6;
    if (wid >= N_NODES) return;
    int l = threadIdx.x & 63;
    float di = dinv[wid];
    unsigned int u = in[(size_t)wid * 64 + l];
    float sc = di * di;
    float ax = sc * bf2f(u & 0xffffu) + bias[2 * l];
    float ay = sc * bf2f(u >> 16) + bias[2 * l + 1];
    int start = offs[wid];
    int n = cnt[wid];

    for (int base = 0; base < n; base += 64) {
        int m = min(n - base, 64);
        int sreg = 0; float wreg = 0.f;
        if (l < m) {
            int2 ev = eidx[start + base + l];
            sreg = ev.x;
            wreg = __int_as_float(ev.y);
        }
        int e = 0;
        for (; e + 4 <= m; e += 4) {
            int s0 = __shfl(sreg, e),     s1 = __shfl(sreg, e + 1);
            int s2 = __shfl(sreg, e + 2), s3 = __shfl(sreg, e + 3);
            float w0 = __shfl(wreg, e),     w1 = __shfl(wreg, e + 1);
            float w2 = __shfl(wreg, e + 2), w3 = __shfl(wreg, e + 3);
            unsigned int u0 = in[(size_t)s0 * 64 + l];
            unsigned int u1 = in[(size_t)s1 * 64 + l];
            unsigned int u2 = in[(size_t)s2 * 64 + l];
            unsigned int u3 = in[(size_t)s3 * 64 + l];
            ax += w0 * bf2f(u0 & 0xffffu); ay += w0 * bf2f(u0 >> 16);
            ax += w1 * bf2f(u1 & 0xffffu); ay += w1 * bf2f(u1 >> 16);
            ax += w2 * bf2f(u2 & 0xffffu); ay += w2 * bf2f(u2 >> 16);
            ax += w3 * bf2f(u3 & 0xffffu); ay += w3 * bf2f(u3 >> 16);
        }
        for (; e < m; ++e) {
            int s0 = __shfl(sreg, e);
            float w0 = __shfl(wreg, e);
            unsigned int u0 = in[(size_t)s0 * 64 + l];
            ax += w0 * bf2f(u0 & 0xffffu); ay += w0 * bf2f(u0 >> 16);
        }
    }
    ax = fmaxf(ax, 0.f); ay = fmaxf(ay, 0.f);   // relu stored: layer 2/3 only need relu(h)
    out[(size_t)wid * 64 + l] = (unsigned int)f2bf(ax) | ((unsigned int)f2bf(ay) << 16);
}

// ---------------- fused agg2+GEMM2 ----------------
// per block of 128 nodes: phase A aggregates g-rows (from relu'd h) into LDS tile,
// phase B: [mu|logvar] = g @ [Wmu|Wlv] + bias via MFMA.
__global__ __launch_bounds__(256) void k_aggemm(const unsigned int* __restrict__ hr,
                                                const int2* __restrict__ eidx,
                                                const int* __restrict__ offs,
                                                const int* __restrict__ cnt,
                                                const float* __restrict__ dinv,
                                                const unsigned short* __restrict__ Wp2,
                                                const float* __restrict__ bias0,
                                                const float* __restrict__ bias1,
                                                float* __restrict__ out) {
    __shared__ unsigned short As[128 * 136];   // g tile bf16, full K=128, stride 136
    __shared__ unsigned short Bs[128 * 40];
    int tid = threadIdx.x, wave = tid >> 6, lane = tid & 63;
    int row0 = blockIdx.x * 128;

    // ---- phase A: wave aggregates 32 nodes
    for (int nn = 0; nn < 32; ++nn) {
        int r = wave * 32 + nn;
        int node = row0 + r;
        float ax = 0.f, ay = 0.f;
        if (node < N_NODES) {
            float di = dinv[node];
            unsigned int u = hr[(size_t)node * 64 + lane];
            float sc = di * di;
            ax = sc * bf2f(u & 0xffffu);
            ay = sc * bf2f(u >> 16);
            int start = offs[node];
            int n = cnt[node];
            for (int base = 0; base < n; base += 64) {
                int m = min(n - base, 64);
                int sreg = 0; float wreg = 0.f;
                if (lane < m) {
                    int2 ev = eidx[start + base + lane];
                    sreg = ev.x;
                    wreg = __int_as_float(ev.y);
                }
                int e = 0;
                for (; e + 4 <= m; e += 4) {
                    int s0 = __shfl(sreg, e),     s1 = __shfl(sreg, e + 1);
                    int s2 = __shfl(sreg, e + 2), s3 = __shfl(sreg, e + 3);
                    float w0 = __shfl(wreg, e),     w1 = __shfl(wreg, e + 1);
                    float w2 = __shfl(wreg, e + 2), w3 = __shfl(wreg, e + 3);
                    unsigned int u0 = hr[(size_t)s0 * 64 + lane];
                    unsigned int u1 = hr[(size_t)s1 * 64 + lane];
                    unsigned int u2 = hr[(size_t)s2 * 64 + lane];
                    unsigned int u3 = hr[(size_t)s3 * 64 + lane];
                    ax += w0 * bf2f(u0 & 0xffffu); ay += w0 * bf2f(u0 >> 16);
                    ax += w1 * bf2f(u1 & 0xffffu); ay += w1 * bf2f(u1 >> 16);
                    ax += w2 * bf2f(u2 & 0xffffu); ay += w2 * bf2f(u2 >> 16);
                    ax += w3 * bf2f(u3 & 0xffffu); ay += w3 * bf2f(u3 >> 16);
                }
                for (; e < m; ++e) {
                    int s0 = __shfl(sreg, e);
                    float w0 = __shfl(wreg, e);
                    unsigned int u0 = hr[(size_t)s0 * 64 + lane];
                    ax += w0 * bf2f(u0 & 0xffffu); ay += w0 * bf2f(u0 >> 16);
                }
            }
        }
        *(unsigned int*)(&As[r * 136 + 2 * lane]) =
            (unsigned int)f2bf(ax) | ((unsigned int)f2bf(ay) << 16);
    }
    __syncthreads();

    // ---- phase B: MFMA with W2
    int c = lane & 15, q = lane >> 4;
    int wrow = (wave >> 1) * 64, wcol = (wave & 1) * 64;
    float4v acc[4][4];
#pragma unroll
    for (int i = 0; i < 4; ++i)
#pragma unroll
        for (int j = 0; j < 4; ++j) acc[i][j] = (float4v){0.f, 0.f, 0.f, 0.f};
    int srow = tid >> 1, shalf = (tid & 1) * 16;

    for (int k0 = 0; k0 < 128; k0 += 32) {
        const unsigned short* bsrc = Wp2 + (size_t)srow * 128 + k0 + shalf;
        short8 b0 = *(const short8*)(bsrc);
        short8 b1 = *(const short8*)(bsrc + 8);
        *(short8*)(&Bs[srow * 40 + shalf])     = b0;
        *(short8*)(&Bs[srow * 40 + shalf + 8]) = b1;
        __syncthreads();
        short8 af[4], bfr[4];
#pragma unroll
        for (int mt = 0; mt < 4; ++mt)
            af[mt] = *(const short8*)(&As[(wrow + mt * 16 + c) * 136 + k0 + q * 8]);
#pragma unroll
        for (int nt = 0; nt < 4; ++nt)
            bfr[nt] = *(const short8*)(&Bs[(wcol + nt * 16 + c) * 40 + q * 8]);
#pragma unroll
        for (int mt = 0; mt < 4; ++mt)
#pragma unroll
            for (int nt = 0; nt < 4; ++nt)
                acc[mt][nt] = __builtin_amdgcn_mfma_f32_16x16x32_bf16(af[mt], bfr[nt], acc[mt][nt], 0, 0, 0);
        __syncthreads();
    }

    // epilogue: mu at 0, logvar at N*64, + bias
#pragma unroll
    for (int mt = 0; mt < 4; ++mt) {
#pragma unroll
        for (int i = 0; i < 4; ++i) {
            int row = row0 + wrow + mt * 16 + q * 4 + i;
            if (row >= N_NODES) continue;
#pragma unroll
            for (int nt = 0; nt < 4; ++nt) {
                int cc = wcol + nt * 16 + c;
                float v = acc[mt][nt][i];
                if (cc < 64) out[(size_t)row * 64 + cc] = v + bias0[cc];
                else out[(size_t)N_NODES * 64 + (size_t)row * 64 + (cc - 64)] = v + bias1[cc - 64];
            }
        }
    }
}

// ---------------- launch ----------------
extern "C" void kernel_launch(void* const* d_in, const int* in_sizes, int n_in,
                              void* d_out, int out_size, void* d_ws, size_t ws_size,
                              hipStream_t stream) {
    const float* x    = (const float*)d_in[0];
    const int*   ei   = (const int*)d_in[1];
    const float* W1   = (const float*)d_in[2];
    const float* b1   = (const float*)d_in[3];
    const float* Wmu  = (const float*)d_in[4];
    const float* bmu  = (const float*)d_in[5];
    const float* Wlv  = (const float*)d_in[6];
    const float* blv  = (const float*)d_in[7];
    float* outp = (float*)d_out;

    const int* src = ei;
    const int* dst = ei + E_EDGES;

    char* ws = (char*)d_ws;
    int*            hist   = (int*)(ws + WS_HIST);
    int*            cursor = (int*)(ws + WS_CURSOR);
    int*            offs   = (int*)(ws + WS_OFFS);
    float*          dinv   = (float*)(ws + WS_DINV);
    int*            bsums  = (int*)(ws + WS_BSUMS);
    int2*           eidx   = (int2*)(ws + WS_EIDX);
    unsigned short* Wp1    = (unsigned short*)(ws + WS_WP1);
    unsigned short* Wp2    = (unsigned short*)(ws + WS_WP2);
    unsigned short* h0     = (unsigned short*)(ws + WS_H0);
    unsigned short* h      = (unsigned short*)(ws + WS_H);

    const int NB_N = (N_NODES + 255) / 256;
    const int NB_E = (E_EDGES + 255) / 256;
    const int NB_S = (N_NODES + 1023) / 1024;
    const int NB_G = (N_NODES + 127) / 128;

    hipMemsetAsync(ws + WS_HIST, 0, 1048576, stream);   // hist + cursor
    k_hist<<<NB_E, 256, 0, stream>>>(dst, hist);
    k_scan1<<<NB_S, 256, 0, stream>>>(hist, offs, bsums, dinv);
    k_scan2<<<1, 128, 0, stream>>>(bsums, NB_S);
    k_scan3<<<NB_N, 256, 0, stream>>>(offs, bsums);
    k_fill<<<NB_E, 256, 0, stream>>>(src, dst, offs, cursor, dinv, eidx);
    k_pack<<<128, 256, 0, stream>>>(W1, Wmu, Wlv, Wp1, Wp2);

    // layer 1
    k_mgemm1<<<NB_G, 256, 0, stream>>>(x, Wp1, h0);
    k_agg1<<<(N_NODES * 64 + 255) / 256, 256, 0, stream>>>(
        (const unsigned int*)h0, (unsigned int*)h, dinv, eidx, offs, hist, b1);

    // layers 2+3 fused
    k_aggemm<<<NB_G, 256, 0, stream>>>(
        (const unsigned int*)h, eidx, offs, hist, dinv, Wp2, bmu, blv, outp);
}

// Round 5
// 361.645 us; speedup vs baseline: 1.1936x; 1.1936x over previous
//
#include <hip/hip_runtime.h>
#include <hip/hip_bf16.h>

#define N_NODES 100000
#define E_EDGES 640000
// channels: IN 256, HID 128, OUT 64+64

typedef __attribute__((ext_vector_type(8))) short short8;
typedef __attribute__((ext_vector_type(4))) float float4v;

__device__ __forceinline__ float bf2f(unsigned int u16) {
    union { unsigned int i; float f; } c; c.i = u16 << 16; return c.f;
}
__device__ __forceinline__ unsigned short f2bf(float f) {
    union { float f; unsigned int i; } c; c.f = f;
    unsigned int x = c.i;
    unsigned int r = (x + 0x7fffu + ((x >> 16) & 1u)) >> 16;   // RNE
    return (unsigned short)r;
}

// async 16B global->LDS (m97 pattern); LDS dst = wave-uniform base + lane*16
#define ASYNC16(g, l)                                                          \
    __builtin_amdgcn_global_load_lds(                                          \
        (const __attribute__((address_space(1))) void*)(g),                    \
        (__attribute__((address_space(3))) void*)(l), 16, 0, 0)

// ---------------- workspace layout (bytes) ----------------
#define WS_HIST    0          // int[100000]
#define WS_CURSOR  524288     // int[100000]   (memset together with hist)
#define WS_OFFS    1048576    // int[100000]
#define WS_DINV    1572864    // float[100000]
#define WS_BSUMS   2097152    // int[256]
#define WS_EIDX    2621440    // int2[640000]  {src, bits(weight)}
#define WS_WP1     7864320    // bf16[128][256] packed W1^T
#define WS_WP2     7929856    // bf16[128][128] packed [Wmu|Wlv]^T
#define WS_H0      7962624    // bf16[100000*128]  x@W1, reused as g after agg2
#define WS_H       33562624   // bf16[100000*128]  relu(A_hat h0 + b1)
// total ~59.2 MB

// ---------------- setup kernels ----------------
__global__ __launch_bounds__(256) void k_hist(const int* __restrict__ dst, int* __restrict__ hist) {
    int e = blockIdx.x * 256 + threadIdx.x;
    if (e < E_EDGES) atomicAdd(&hist[dst[e]], 1);
}

// scan level 1 (+ dinv computed on the side)
__global__ __launch_bounds__(256) void k_scan1(const int* __restrict__ hist,
                                               int* __restrict__ offs,
                                               int* __restrict__ bsums,
                                               float* __restrict__ dinv) {
    __shared__ int sd[256];
    int t = threadIdx.x;
    int base = blockIdx.x * 1024 + t * 4;
    int v[4];
#pragma unroll
    for (int j = 0; j < 4; ++j) v[j] = (base + j < N_NODES) ? hist[base + j] : 0;
#pragma unroll
    for (int j = 0; j < 4; ++j)
        if (base + j < N_NODES) dinv[base + j] = rsqrtf((float)(v[j] + 1));
    int s = v[0] + v[1] + v[2] + v[3];
    sd[t] = s;
    __syncthreads();
    for (int d = 1; d < 256; d <<= 1) {
        int x = (t >= d) ? sd[t - d] : 0;
        __syncthreads();
        sd[t] += x;
        __syncthreads();
    }
    int excl = sd[t] - s;
    if (t == 255) bsums[blockIdx.x] = sd[255];
    int run = excl;
#pragma unroll
    for (int j = 0; j < 4; ++j) {
        if (base + j < N_NODES) offs[base + j] = run;
        run += v[j];
    }
}

__global__ __launch_bounds__(128) void k_scan2(int* __restrict__ bsums, int nb) {
    __shared__ int sd[128];
    int t = threadIdx.x;
    int v = (t < nb) ? bsums[t] : 0;
    sd[t] = v;
    __syncthreads();
    for (int d = 1; d < 128; d <<= 1) {
        int x = (t >= d) ? sd[t - d] : 0;
        __syncthreads();
        sd[t] += x;
        __syncthreads();
    }
    if (t < nb) bsums[t] = sd[t] - v;
}

__global__ __launch_bounds__(256) void k_scan3(int* __restrict__ offs, const int* __restrict__ bsums) {
    int i = blockIdx.x * 256 + threadIdx.x;
    if (i < N_NODES) offs[i] += bsums[i >> 10];
}

// CSR fill: (src, weight) packed into one int2 -> one scattered line per edge
__global__ __launch_bounds__(256) void k_fill(const int* __restrict__ src, const int* __restrict__ dst,
                                              const int* __restrict__ offs, int* __restrict__ cursor,
                                              const float* __restrict__ dinv,
                                              int2* __restrict__ eidx) {
    int e = blockIdx.x * 256 + threadIdx.x;
    if (e < E_EDGES) {
        int s = src[e], d = dst[e];
        int p = offs[d] + atomicAdd(&cursor[d], 1);
        int2 v;
        v.x = s;
        v.y = __float_as_int(dinv[s] * dinv[d]);
        eidx[p] = v;
    }
}

// pack weights to bf16 [n][k] (B^T) layout; W2 = [Wmu | Wlv] columns
__global__ __launch_bounds__(256) void k_pack(const float* __restrict__ W1,
                                              const float* __restrict__ Wmu,
                                              const float* __restrict__ Wlv,
                                              unsigned short* __restrict__ Wp1,
                                              unsigned short* __restrict__ Wp2) {
    int i = blockIdx.x * 256 + threadIdx.x;
    if (i < 256 * 128) {
        int k = i >> 7, n = i & 127;
        Wp1[n * 256 + k] = f2bf(W1[i]);
    }
    if (i < 128 * 128) {
        int k = i >> 7, n = i & 127;
        float w = (n < 64) ? Wmu[k * 64 + n] : Wlv[k * 64 + (n - 64)];
        Wp2[n * 128 + k] = f2bf(w);
    }
}

// ---------------- GEMM1: h0[N][128] = bf16(x[N][256]) @ W1 ----------------
// A fp32 staged via global_load_lds w/ XOR-swizzled source mapping:
//   LDS chunk position j of row r holds kq = j ^ (r&7)  (16B fp32 chunks, 8/row)
__global__ __launch_bounds__(256) void k_mgemm1(const float* __restrict__ A,
                                                const unsigned short* __restrict__ Bpack,
                                                unsigned short* __restrict__ out) {
    __shared__ float As[128 * 32];          // 16 KB, one K-chunk, swizzled
    __shared__ unsigned short Bs[128 * 40]; // 10 KB, padded stride 40
    int tid = threadIdx.x;
    int row0 = blockIdx.x * 128;
    int wave = tid >> 6, lane = tid & 63;
    int c = lane & 15, q = lane >> 4;
    int wrow = (wave >> 1) * 64, wcol = (wave & 1) * 64;

    float4v acc[4][4];
#pragma unroll
    for (int i = 0; i < 4; ++i)
#pragma unroll
        for (int j = 0; j < 4; ++j) acc[i][j] = (float4v){0.f, 0.f, 0.f, 0.f};

    int srow = tid >> 1;          // B stage: n-row
    int shalf = (tid & 1) * 16;   // B stage: k half

    for (int k0 = 0; k0 < 256; k0 += 32) {
        const unsigned short* bsrc = Bpack + (size_t)srow * 256 + k0 + shalf;
        short8 b0 = *(const short8*)(bsrc);
        short8 b1 = *(const short8*)(bsrc + 8);
#pragma unroll
        for (int t = 0; t < 4; ++t) {
            int S = (t * 4 + wave) * 64 + lane;   // slot
            int row = S >> 3, j = S & 7;
            int kq = j ^ (row & 7);
            const float* g = A + (size_t)(row0 + row) * 256 + k0 + kq * 4;
            float* ldst = As + (t * 4 + wave) * 256;   // wave-uniform base
            if (row0 + row < N_NODES) ASYNC16(g, ldst);
        }
        *(short8*)(&Bs[srow * 40 + shalf])     = b0;
        *(short8*)(&Bs[srow * 40 + shalf + 8]) = b1;
        __syncthreads();

        short8 af[4], bfr[4];
#pragma unroll
        for (int mt = 0; mt < 4; ++mt) {
            int r = wrow + mt * 16 + c;
            int j0 = (q * 2) ^ (r & 7);
            float4v fa = *(const float4v*)(&As[r * 32 + j0 * 4]);        // k = q*8..+3
            float4v fb = *(const float4v*)(&As[r * 32 + (j0 ^ 1) * 4]);  // k = q*8+4..+7
            short8 s;
#pragma unroll
            for (int jj = 0; jj < 4; ++jj) s[jj]     = (short)f2bf(fa[jj]);
#pragma unroll
            for (int jj = 0; jj < 4; ++jj) s[4 + jj] = (short)f2bf(fb[jj]);
            af[mt] = s;
        }
#pragma unroll
        for (int nt = 0; nt < 4; ++nt)
            bfr[nt] = *(const short8*)(&Bs[(wcol + nt * 16 + c) * 40 + q * 8]);
#pragma unroll
        for (int mt = 0; mt < 4; ++mt)
#pragma unroll
            for (int nt = 0; nt < 4; ++nt)
                acc[mt][nt] = __builtin_amdgcn_mfma_f32_16x16x32_bf16(af[mt], bfr[nt], acc[mt][nt], 0, 0, 0);
        __syncthreads();
    }

    // epilogue: bf16 out. D: col = lane&15, row = q*4 + reg
#pragma unroll
    for (int mt = 0; mt < 4; ++mt) {
#pragma unroll
        for (int i = 0; i < 4; ++i) {
            int row = row0 + wrow + mt * 16 + q * 4 + i;
            if (row >= N_NODES) continue;
#pragma unroll
            for (int nt = 0; nt < 4; ++nt) {
                int cc = wcol + nt * 16 + c;
                out[(size_t)row * 128 + cc] = f2bf(acc[mt][nt][i]);
            }
        }
    }
}

// ---------------- GEMM2: [mu|logvar] = g[N][128] @ W2 + bias, fp32 out ----------------
__global__ __launch_bounds__(256) void k_mgemm2(const unsigned short* __restrict__ A,
                                                const unsigned short* __restrict__ Bpack,
                                                const float* __restrict__ bias0,
                                                const float* __restrict__ bias1,
                                                float* __restrict__ out) {
    constexpr int LDT = 40;
    __shared__ unsigned short As[128 * LDT];
    __shared__ unsigned short Bs[128 * LDT];
    int tid = threadIdx.x;
    int row0 = blockIdx.x * 128;
    int wave = tid >> 6, lane = tid & 63;
    int c = lane & 15, q = lane >> 4;
    int wrow = (wave >> 1) * 64, wcol = (wave & 1) * 64;

    float4v acc[4][4];
#pragma unroll
    for (int i = 0; i < 4; ++i)
#pragma unroll
        for (int j = 0; j < 4; ++j) acc[i][j] = (float4v){0.f, 0.f, 0.f, 0.f};

    int srow = tid >> 1, shalf = (tid & 1) * 16;
    const short8 zed = {0, 0, 0, 0, 0, 0, 0, 0};

    for (int k0 = 0; k0 < 128; k0 += 32) {
        const unsigned short* bsrc = Bpack + (size_t)srow * 128 + k0 + shalf;
        short8 b0 = *(const short8*)(bsrc);
        short8 b1 = *(const short8*)(bsrc + 8);
        int grow = row0 + srow;
        short8 a0 = zed, a1 = zed;
        if (grow < N_NODES) {
            const unsigned short* asrc = A + (size_t)grow * 128 + k0 + shalf;
            a0 = *(const short8*)(asrc);
            a1 = *(const short8*)(asrc + 8);
        }
        *(short8*)(&Bs[srow * LDT + shalf])     = b0;
        *(short8*)(&Bs[srow * LDT + shalf + 8]) = b1;
        *(short8*)(&As[srow * LDT + shalf])     = a0;
        *(short8*)(&As[srow * LDT + shalf + 8]) = a1;
        __syncthreads();

        short8 af[4], bfr[4];
#pragma unroll
        for (int mt = 0; mt < 4; ++mt)
            af[mt] = *(const short8*)(&As[(wrow + mt * 16 + c) * LDT + q * 8]);
#pragma unroll
        for (int nt = 0; nt < 4; ++nt)
            bfr[nt] = *(const short8*)(&Bs[(wcol + nt * 16 + c) * LDT + q * 8]);
#pragma unroll
        for (int mt = 0; mt < 4; ++mt)
#pragma unroll
            for (int nt = 0; nt < 4; ++nt)
                acc[mt][nt] = __builtin_amdgcn_mfma_f32_16x16x32_bf16(af[mt], bfr[nt], acc[mt][nt], 0, 0, 0);
        __syncthreads();
    }

    // epilogue: mu at 0, logvar at N*64
#pragma unroll
    for (int mt = 0; mt < 4; ++mt) {
#pragma unroll
        for (int i = 0; i < 4; ++i) {
            int row = row0 + wrow + mt * 16 + q * 4 + i;
            if (row >= N_NODES) continue;
#pragma unroll
            for (int nt = 0; nt < 4; ++nt) {
                int cc = wcol + nt * 16 + c;
                float v = acc[mt][nt][i];
                if (cc < 64) out[(size_t)row * 64 + cc] = v + bias0[cc];
                else out[(size_t)N_NODES * 64 + (size_t)row * 64 + (cc - 64)] = v + bias1[cc - 64];
            }
        }
    }
}

// ---------------- aggregation: one wave per node, lane-parallel edge prefetch ----------------
// BIAS_RELU=1: out = relu(A_hat in + b)  (layer 1).  BIAS_RELU=0: out = A_hat in  (layer 2, in pre-relu'd).
template <int BIAS_RELU>
__global__ __launch_bounds__(256) void k_agg(const unsigned int* __restrict__ in,
                                             unsigned int* __restrict__ out,
                                             const float* __restrict__ dinv,
                                             const int2* __restrict__ eidx,
                                             const int* __restrict__ offs,
                                             const int* __restrict__ cnt,
                                             const float* __restrict__ bias) {
    int wid = (blockIdx.x * 256 + threadIdx.x) >> 6;
    if (wid >= N_NODES) return;
    int l = threadIdx.x & 63;
    float di = dinv[wid];
    unsigned int u = in[(size_t)wid * 64 + l];
    float sc = di * di;
    float ax = sc * bf2f(u & 0xffffu);
    float ay = sc * bf2f(u >> 16);
    if (BIAS_RELU) { ax += bias[2 * l]; ay += bias[2 * l + 1]; }
    int start = offs[wid];
    int n = cnt[wid];

    for (int base = 0; base < n; base += 64) {
        int m = min(n - base, 64);
        int sreg = 0; float wreg = 0.f;
        if (l < m) {
            int2 ev = eidx[start + base + l];
            sreg = ev.x;
            wreg = __int_as_float(ev.y);
        }
        int e = 0;
        for (; e + 4 <= m; e += 4) {
            int s0 = __shfl(sreg, e),     s1 = __shfl(sreg, e + 1);
            int s2 = __shfl(sreg, e + 2), s3 = __shfl(sreg, e + 3);
            float w0 = __shfl(wreg, e),     w1 = __shfl(wreg, e + 1);
            float w2 = __shfl(wreg, e + 2), w3 = __shfl(wreg, e + 3);
            unsigned int u0 = in[(size_t)s0 * 64 + l];
            unsigned int u1 = in[(size_t)s1 * 64 + l];
            unsigned int u2 = in[(size_t)s2 * 64 + l];
            unsigned int u3 = in[(size_t)s3 * 64 + l];
            ax += w0 * bf2f(u0 & 0xffffu); ay += w0 * bf2f(u0 >> 16);
            ax += w1 * bf2f(u1 & 0xffffu); ay += w1 * bf2f(u1 >> 16);
            ax += w2 * bf2f(u2 & 0xffffu); ay += w2 * bf2f(u2 >> 16);
            ax += w3 * bf2f(u3 & 0xffffu); ay += w3 * bf2f(u3 >> 16);
        }
        for (; e < m; ++e) {
            int s0 = __shfl(sreg, e);
            float w0 = __shfl(wreg, e);
            unsigned int u0 = in[(size_t)s0 * 64 + l];
            ax += w0 * bf2f(u0 & 0xffffu); ay += w0 * bf2f(u0 >> 16);
        }
    }
    if (BIAS_RELU) { ax = fmaxf(ax, 0.f); ay = fmaxf(ay, 0.f); }   // store relu'd h
    out[(size_t)wid * 64 + l] = (unsigned int)f2bf(ax) | ((unsigned int)f2bf(ay) << 16);
}

// ---------------- launch ----------------
extern "C" void kernel_launch(void* const* d_in, const int* in_sizes, int n_in,
                              void* d_out, int out_size, void* d_ws, size_t ws_size,
                              hipStream_t stream) {
    const float* x    = (const float*)d_in[0];
    const int*   ei   = (const int*)d_in[1];
    const float* W1   = (const float*)d_in[2];
    const float* b1   = (const float*)d_in[3];
    const float* Wmu  = (const float*)d_in[4];
    const float* bmu  = (const float*)d_in[5];
    const float* Wlv  = (const float*)d_in[6];
    const float* blv  = (const float*)d_in[7];
    float* outp = (float*)d_out;

    const int* src = ei;
    const int* dst = ei + E_EDGES;

    char* ws = (char*)d_ws;
    int*            hist   = (int*)(ws + WS_HIST);
    int*            cursor = (int*)(ws + WS_CURSOR);
    int*            offs   = (int*)(ws + WS_OFFS);
    float*          dinv   = (float*)(ws + WS_DINV);
    int*            bsums  = (int*)(ws + WS_BSUMS);
    int2*           eidx   = (int2*)(ws + WS_EIDX);
    unsigned short* Wp1    = (unsigned short*)(ws + WS_WP1);
    unsigned short* Wp2    = (unsigned short*)(ws + WS_WP2);
    unsigned short* h0     = (unsigned short*)(ws + WS_H0);   // x@W1, reused as g
    unsigned short* h      = (unsigned short*)(ws + WS_H);    // relu(A_hat h0 + b1)

    const int NB_N = (N_NODES + 255) / 256;
    const int NB_E = (E_EDGES + 255) / 256;
    const int NB_S = (N_NODES + 1023) / 1024;
    const int NB_G = (N_NODES + 127) / 128;

    hipMemsetAsync(ws + WS_HIST, 0, 1048576, stream);   // hist + cursor
    k_hist<<<NB_E, 256, 0, stream>>>(dst, hist);
    k_scan1<<<NB_S, 256, 0, stream>>>(hist, offs, bsums, dinv);
    k_scan2<<<1, 128, 0, stream>>>(bsums, NB_S);
    k_scan3<<<NB_N, 256, 0, stream>>>(offs, bsums);
    k_fill<<<NB_E, 256, 0, stream>>>(src, dst, offs, cursor, dinv, eidx);
    k_pack<<<128, 256, 0, stream>>>(W1, Wmu, Wlv, Wp1, Wp2);

    // layer 1: h0 = bf16(x) @ W1 ; h = relu(A_hat h0 + b1)
    k_mgemm1<<<NB_G, 256, 0, stream>>>(x, Wp1, h0);
    k_agg<1><<<(N_NODES * 64 + 255) / 256, 256, 0, stream>>>(
        (const unsigned int*)h0, (unsigned int*)h, dinv, eidx, offs, hist, b1);

    // layers 2+3: g = A_hat h (h already relu'd) ; [mu|logvar] = g @ W2 + bias
    k_agg<0><<<(N_NODES * 64 + 255) / 256, 256, 0, stream>>>(
        (const unsigned int*)h, (unsigned int*)h0, dinv, eidx, offs, hist, nullptr);
    k_mgemm2<<<NB_G, 256, 0, stream>>>(h0, Wp2, bmu, blv, outp);
}